// Round 13
// baseline (214.392 us; speedup 1.0000x reference)
//
#include <hip/hip_runtime.h>

#define Bsz 4
#define Nn  256
#define OBSD 40
#define ACTD 8
#define HEADS 8
#define DIMD 32
#define Td  256

#define FMA4(accr, s, wv) \
    (accr).x = fmaf((s), (wv).x, (accr).x); \
    (accr).y = fmaf((s), (wv).y, (accr).y); \
    (accr).z = fmaf((s), (wv).z, (accr).z); \
    (accr).w = fmaf((s), (wv).w, (accr).w)

// K1: emb = relu(relu(obs @ We1 + be1) @ We2 + be2).
// 128 blocks x 512 threads. Wave wv owns emb row g*8+wv COMPLETELY (full K),
// lane c owns cols 4c..4c+3. Per-row operands come from wave-uniform LDS
// broadcasts; h1 is written and read by the SAME wave (no barrier needed).
// All 8 waves stream identical We1/We2 addresses -> L1 drafting.
__global__ __launch_bounds__(512, 1) void k_emb(
        const float* __restrict__ x,
        const float* __restrict__ We1, const float* __restrict__ be1,
        const float* __restrict__ We2, const float* __restrict__ be2,
        float* __restrict__ emb,
        float* __restrict__ snh, float* __restrict__ shid) {
    int g = blockIdx.x, t = threadIdx.x;
    int wv = t >> 6, c = t & 63;
    int row = g * 8 + wv;                 // this wave's emb row (b*N + n)
    int b = row >> 8, nrow = row & 255;

    __shared__ float obsT[OBSD][8];       // obsT[k][r] = obs row (g*8+r), chan k
    __shared__ float h1L[8][Td];          // per-wave hidden row

    if (g == 0)      { snh[t] = 0.f;  snh[t + 512] = 0.f; }
    else if (g == 1) { shid[t] = 0.f; shid[t + 512] = 0.f; }

    for (int i = t; i < OBSD * 8; i += 512) {
        int k = i >> 3, r = i & 7;
        int rr = g * 8 + r;
        obsT[k][r] = x[((rr >> 8) * (Nn + 1) + (rr & 255)) * OBSD + k];
    }
    __syncthreads();

    // Layer 1 (K=40): 4-deep rotating prefetch on We1.
    float4 a1 = *(const float4*)(be1 + 4 * c);
    {
        float4 buf[4];
#pragma unroll
        for (int p = 0; p < 4; ++p) buf[p] = *(const float4*)(We1 + p * Td + 4 * c);
#pragma unroll
        for (int k = 0; k < OBSD; ++k) {
            float4 w4 = buf[k & 3];
            if (k + 4 < OBSD) buf[k & 3] = *(const float4*)(We1 + (k + 4) * Td + 4 * c);
            float o = obsT[k][wv];        // wave-uniform broadcast
            FMA4(a1, o, w4);
        }
    }
    a1.x = fmaxf(a1.x, 0.f); a1.y = fmaxf(a1.y, 0.f);
    a1.z = fmaxf(a1.z, 0.f); a1.w = fmaxf(a1.w, 0.f);
    *(float4*)&h1L[wv][4 * c] = a1;       // same-wave write (lgkmcnt only)

    // Layer 2 (K=256): 8-deep rotating prefetch on We2.
    float4 a2 = *(const float4*)(be2 + 4 * c);
    {
        float4 buf[8];
#pragma unroll
        for (int p = 0; p < 8; ++p) buf[p] = *(const float4*)(We2 + p * Td + 4 * c);
#pragma unroll 8
        for (int k = 0; k < Td; ++k) {
            float4 w4 = buf[k & 7];
            if (k + 8 < Td) buf[k & 7] = *(const float4*)(We2 + (k + 8) * Td + 4 * c);
            float hk = h1L[wv][k];        // same-wave read, broadcast
            FMA4(a2, hk, w4);
        }
    }
    a2.x = fmaxf(a2.x, 0.f); a2.y = fmaxf(a2.y, 0.f);
    a2.z = fmaxf(a2.z, 0.f); a2.w = fmaxf(a2.w, 0.f);
    *(float4*)&emb[row * Td + 4 * c] = a2;
}

// K2: ne + relu(ne@Wn/Wh) column-sums. grid (32, B) x 512 threads.
// Wave wv owns j-row j0+wv completely: phase 1 computes ne[j] (full K),
// stores it in its own LDS slot (same-wave), phase 2 computes the COMPLETE
// dot products relu(ne_j@Wn + bn) / (Wh,bh) -> exact relu per wave, then one
// barrier + 8-way j-sum + atomics. All waves stream identical emb/Wn/Wh
// addresses -> L1 drafting.
__global__ __launch_bounds__(512, 1) void k_fused(
        const float* __restrict__ adj, const float* __restrict__ emb,
        const float* __restrict__ Wn, const float* __restrict__ bn,
        const float* __restrict__ Wh, const float* __restrict__ bh,
        float* __restrict__ snh, float* __restrict__ shid) {
    int gx = blockIdx.x, b = blockIdx.y;
    int t = threadIdx.x;
    int wv = t >> 6, c = t & 63;
    int j0 = gx * 8;

    __shared__ float adjT[Nn][9];         // padded: write stride 9 (conflict-free)
    __shared__ float neL[8][Td];          // per-wave ne row
    __shared__ float4 partN[8][64];       // per-wave relu'd contributions
    __shared__ float4 partH[8][64];

    for (int i = t; i < Nn * 8; i += 512) {
        int n = i & 255, r = i >> 8;
        adjT[n][r] = adj[(j0 + r) * Nn + n];   // coalesced read over n
    }
    __syncthreads();

    const float* eb = emb + b * Nn * Td;

    // Phase 1: ne[j0+wv][4c..4c+3], full n-stream, 8-deep prefetch.
    float4 accN = {};
    {
        float4 buf[8];
#pragma unroll
        for (int p = 0; p < 8; ++p) buf[p] = *(const float4*)(eb + p * Td + 4 * c);
#pragma unroll 8
        for (int n = 0; n < Nn; ++n) {
            float4 e4 = buf[n & 7];
            if (n + 8 < Nn) buf[n & 7] = *(const float4*)(eb + (n + 8) * Td + 4 * c);
            float a = adjT[n][wv];        // wave-uniform broadcast
            FMA4(accN, a, e4);
        }
    }
    *(float4*)&neL[wv][4 * c] = accN;     // same-wave write

    // Phase 2: complete dot products vs Wn/Wh, 4+4 rotating prefetch.
    float4 sN = *(const float4*)(bn + 4 * c);
    float4 sH = *(const float4*)(bh + 4 * c);
    {
        float4 bufN[4], bufH[4];
#pragma unroll
        for (int p = 0; p < 4; ++p) {
            bufN[p] = *(const float4*)(Wn + p * Td + 4 * c);
            bufH[p] = *(const float4*)(Wh + p * Td + 4 * c);
        }
#pragma unroll 4
        for (int k = 0; k < Td; ++k) {
            float4 wn4 = bufN[k & 3];
            float4 wh4 = bufH[k & 3];
            if (k + 4 < Td) {
                bufN[k & 3] = *(const float4*)(Wn + (k + 4) * Td + 4 * c);
                bufH[k & 3] = *(const float4*)(Wh + (k + 4) * Td + 4 * c);
            }
            float nk = neL[wv][k];        // same-wave read, broadcast
            FMA4(sN, nk, wn4);
            FMA4(sH, nk, wh4);
        }
    }
    sN.x = fmaxf(sN.x, 0.f); sN.y = fmaxf(sN.y, 0.f);
    sN.z = fmaxf(sN.z, 0.f); sN.w = fmaxf(sN.w, 0.f);
    sH.x = fmaxf(sH.x, 0.f); sH.y = fmaxf(sH.y, 0.f);
    sH.z = fmaxf(sH.z, 0.f); sH.w = fmaxf(sH.w, 0.f);
    partN[wv][c] = sN;
    partH[wv][c] = sH;
    __syncthreads();                      // the ONLY data barrier

    if (t < Td) {
        int c2 = t >> 2, jj = t & 3;
        float v1 = 0.f, v2 = 0.f;
#pragma unroll
        for (int w = 0; w < 8; ++w) {
            v1 += ((const float*)&partN[w][c2])[jj];
            v2 += ((const float*)&partH[w][c2])[jj];
        }
        atomicAdd(&snh[b * Td + t], v1);
        atomicAdd(&shid[b * Td + t], v2);
    }
}

// K3: per-batch target row -> ah -> softmax over DIM per head -> mean -> Wa
__global__ __launch_bounds__(256, 1) void k_final(
        const float* __restrict__ x, const float* __restrict__ emb,
        const float* __restrict__ Wl, const float* __restrict__ bl,
        const float* __restrict__ snh, const float* __restrict__ shid,
        const float* __restrict__ Wa, const float* __restrict__ ba,
        float* __restrict__ out) {
    int b = blockIdx.x;
    int t = threadIdx.x;
    int tgt = (int)x[(b * (Nn + 1) + Nn) * OBSD + 0];
    tgt = tgt < 0 ? 0 : (tgt > Nn - 1 ? Nn - 1 : tgt);
    __shared__ float erow[Td], lg[Td], p[Td], od[DIMD];
    __shared__ float4 partL[4][64];
    erow[t] = emb[(b * Nn + tgt) * Td + t];
    __syncthreads();

    int wv = t >> 6, c = t & 63;
    {
        float4 aL = {};
        float4 buf[8];
#pragma unroll
        for (int pp = 0; pp < 8; ++pp)
            buf[pp] = *(const float4*)(Wl + ((wv << 6) + pp) * Td + 4 * c);
#pragma unroll
        for (int i = 0; i < 64; ++i) {
            int k = (wv << 6) + i;
            float4 wlv = buf[i & 7];
            if (i + 8 < 64)
                buf[i & 7] = *(const float4*)(Wl + (k + 8) * Td + 4 * c);
            FMA4(aL, erow[k], wlv);
        }
        partL[wv][c] = aL;
    }
    __syncthreads();

    int c2 = t >> 2, j = t & 3;
    float acc = bl[t];
#pragma unroll
    for (int w2 = 0; w2 < 4; ++w2) acc += ((const float*)&partL[w2][c2])[j];
    float ah = fmaxf(acc, 0.f);
    lg[t] = ah * snh[b * Td + t];
    __syncthreads();
    int h = t & 7;
    float mx = -1e30f;
#pragma unroll
    for (int d = 0; d < DIMD; ++d) mx = fmaxf(mx, lg[d * HEADS + h]);
    float se = 0.f;
#pragma unroll
    for (int d = 0; d < DIMD; ++d) se += __expf(lg[d * HEADS + h] - mx);
    float attn = __expf(lg[t] - mx) / se;
    p[t] = attn * shid[b * Td + t];
    __syncthreads();
    if (t < DIMD) {
        float s = 0.f;
#pragma unroll
        for (int hh = 0; hh < HEADS; ++hh) s += p[t * HEADS + hh];
        od[t] = s * (1.f / HEADS);
    }
    __syncthreads();
    if (t < ACTD) {
        float s = ba[t];
#pragma unroll
        for (int d = 0; d < DIMD; ++d) s = fmaf(od[d], Wa[d * ACTD + t], s);
        out[b * ACTD + t] = s;
    }
}

extern "C" void kernel_launch(void* const* d_in, const int* in_sizes, int n_in,
                              void* d_out, int out_size, void* d_ws, size_t ws_size,
                              hipStream_t stream) {
    const float* x   = (const float*)d_in[0];
    const float* adj = (const float*)d_in[1];
    const float* We1 = (const float*)d_in[2];
    const float* be1 = (const float*)d_in[3];
    const float* We2 = (const float*)d_in[4];
    const float* be2 = (const float*)d_in[5];
    const float* Wl  = (const float*)d_in[6];
    const float* bl  = (const float*)d_in[7];
    const float* Wn  = (const float*)d_in[8];
    const float* bn  = (const float*)d_in[9];
    const float* Wh  = (const float*)d_in[10];
    const float* bh  = (const float*)d_in[11];
    const float* Wa  = (const float*)d_in[12];
    const float* ba  = (const float*)d_in[13];
    float* out = (float*)d_out;

    // ws layout: emb f32[B*N*T] (1 MB) | snh f32[B*T] | shid f32[B*T]
    float* emb  = (float*)d_ws;
    float* snh  = emb + Bsz * Nn * Td;
    float* shid = snh + Bsz * Td;

    k_emb<<<dim3(Bsz * Nn / 8), dim3(512), 0, stream>>>(x, We1, be1, We2, be2,
                                                        emb, snh, shid);
    k_fused<<<dim3(Nn / 8, Bsz), dim3(512), 0, stream>>>(adj, emb, Wn, bn, Wh, bh,
                                                         snh, shid);
    k_final<<<dim3(Bsz), dim3(256), 0, stream>>>(x, emb, Wl, bl, snh, shid,
                                                 Wa, ba, out);
}

// Round 15
// 100.865 us; speedup vs baseline: 2.1255x; 2.1255x over previous
//
#include <hip/hip_runtime.h>

#define Bsz 4
#define Nn  256
#define OBSD 40
#define ACTD 8
#define HEADS 8
#define DIMD 32
#define Td  256
#define R   4   // rows per block

#define FMA4(accr, s, wv) do { \
    (accr).x = fmaf((s), (wv).x, (accr).x); \
    (accr).y = fmaf((s), (wv).y, (accr).y); \
    (accr).z = fmaf((s), (wv).z, (accr).z); \
    (accr).w = fmaf((s), (wv).w, (accr).w); } while (0)

// K1: emb = relu(relu(obs @ We1 + be1) @ We2 + be2), R=4 rows per block.
// grid = 256 blocks x 512 threads. Chunked load-groups (8 loads in flight).
__global__ __launch_bounds__(512, 1) void k_emb(
                      const float* __restrict__ x,
                      const float* __restrict__ We1, const float* __restrict__ be1,
                      const float* __restrict__ We2, const float* __restrict__ be2,
                      float* __restrict__ emb,
                      float* __restrict__ snh, float* __restrict__ shid) {
    int g = blockIdx.x;
    int t = threadIdx.x;                 // 0..511
    int row0 = g * R;
    int b = row0 >> 8;
    int n0 = row0 & 255;
    if (g == 0)      { for (int i = t; i < Bsz * Td; i += 512) snh[i]  = 0.f; }
    else if (g == 1) { for (int i = t; i < Bsz * Td; i += 512) shid[i] = 0.f; }

    __shared__ float4 obs_t[OBSD];       // 4 rows per obs-channel
    __shared__ float4 h1_t[Td];          // 4 rows per hidden channel
    __shared__ float4 part[8][R][64];    // [wave][row][colgroup] partials (32 KB)
    if (t < R * OBSD) {
        int r = t & (R - 1), k = t >> 2;
        ((float*)&obs_t[k])[r] = x[(b * (Nn + 1) + n0 + r) * OBSD + k];
    }
    __syncthreads();

    // Layer 1 (K=40): threads 0..255 own one column; 5 chunks of 8 grouped loads.
    if (t < Td) {
        float bias1 = be1[t];
        float a1[R] = {bias1, bias1, bias1, bias1};
#pragma unroll
        for (int ch = 0; ch < 5; ++ch) {
            float w[8];
#pragma unroll
            for (int p = 0; p < 8; ++p) w[p] = We1[(ch * 8 + p) * Td + t];
#pragma unroll
            for (int p = 0; p < 8; ++p) {
                float4 ov = obs_t[ch * 8 + p];
                a1[0] = fmaf(ov.x, w[p], a1[0]);
                a1[1] = fmaf(ov.y, w[p], a1[1]);
                a1[2] = fmaf(ov.z, w[p], a1[2]);
                a1[3] = fmaf(ov.w, w[p], a1[3]);
            }
        }
        h1_t[t] = make_float4(fmaxf(a1[0], 0.f), fmaxf(a1[1], 0.f),
                              fmaxf(a1[2], 0.f), fmaxf(a1[3], 0.f));
    }
    __syncthreads();

    // Layer 2: wave wv handles k in [32wv, +32); 4 chunks of 8 grouped loads.
    int wv = t >> 6, c = t & 63;
    {
        float4 a2[R] = {};
#pragma unroll
        for (int ch = 0; ch < 4; ++ch) {
            int k0 = (wv << 5) + ch * 8;
            float4 w[8];
#pragma unroll
            for (int p = 0; p < 8; ++p)
                w[p] = *(const float4*)(We2 + (k0 + p) * Td + 4 * c);
#pragma unroll
            for (int p = 0; p < 8; ++p) {
                float4 hv = h1_t[k0 + p];
                FMA4(a2[0], hv.x, w[p]);
                FMA4(a2[1], hv.y, w[p]);
                FMA4(a2[2], hv.z, w[p]);
                FMA4(a2[3], hv.w, w[p]);
            }
        }
#pragma unroll
        for (int r = 0; r < R; ++r) part[wv][r][c] = a2[r];
    }
    __syncthreads();

    if (t < Td) {
        int c2 = t >> 2, j = t & 3;
#pragma unroll
        for (int r = 0; r < R; ++r) {
            float v = be2[t];
#pragma unroll
            for (int w2 = 0; w2 < 8; ++w2) v += ((const float*)&part[w2][r][c2])[j];
            emb[(row0 + r) * Td + t] = fmaxf(v, 0.f);
        }
    }
}

// K2: fused ne + Wn/Wh column-sum, R=4 m-rows per block.
// grid = (64, 4) x 512 threads. Chunked load-groups throughout.
__global__ __launch_bounds__(512, 1) void k_fused(
                        const float* __restrict__ adj, const float* __restrict__ emb,
                        const float* __restrict__ Wn, const float* __restrict__ bn,
                        const float* __restrict__ Wh, const float* __restrict__ bh,
                        float* __restrict__ snh, float* __restrict__ shid) {
    int g = blockIdx.x, b = blockIdx.y;
    int t = threadIdx.x;                 // 0..511
    int m0 = g * R;
    __shared__ float4 arow_t[Nn];        // 4 KB
    __shared__ float4 nrow_t[Td];        // 4 KB
    __shared__ float4 partN[8][R][64];   // 32 KB
    __shared__ float4 partH[8][R][64];   // 32 KB
    if (t < Td)
        arow_t[t] = make_float4(adj[(m0 + 0) * Nn + t], adj[(m0 + 1) * Nn + t],
                                adj[(m0 + 2) * Nn + t], adj[(m0 + 3) * Nn + t]);
    __syncthreads();

    int wv = t >> 6, c = t & 63;
    const float* eb = emb + b * Nn * Td;

    // Phase 1: ne. Wave wv sums n in [32wv, +32); 4 chunks of 8 grouped loads.
    {
        float4 aN[R] = {};
#pragma unroll
        for (int ch = 0; ch < 4; ++ch) {
            int n0c = (wv << 5) + ch * 8;
            float4 e[8];
#pragma unroll
            for (int p = 0; p < 8; ++p)
                e[p] = *(const float4*)(eb + (n0c + p) * Td + 4 * c);
#pragma unroll
            for (int p = 0; p < 8; ++p) {
                float4 ar = arow_t[n0c + p];
                FMA4(aN[0], ar.x, e[p]);
                FMA4(aN[1], ar.y, e[p]);
                FMA4(aN[2], ar.z, e[p]);
                FMA4(aN[3], ar.w, e[p]);
            }
        }
#pragma unroll
        for (int r = 0; r < R; ++r) partN[wv][r][c] = aN[r];
    }
    __syncthreads();
    if (t < Td) {
        int c2 = t >> 2, j = t & 3;
        float nr[R];
#pragma unroll
        for (int r = 0; r < R; ++r) {
            float v = 0.f;
#pragma unroll
            for (int w2 = 0; w2 < 8; ++w2) v += ((const float*)&partN[w2][r][c2])[j];
            nr[r] = v;
        }
        nrow_t[t] = make_float4(nr[0], nr[1], nr[2], nr[3]);
    }
    __syncthreads();

    // Phase 2: Wn/Wh dual stream; 8 chunks of (4 Wn + 4 Wh) grouped loads.
    {
        float4 sN[R] = {};
        float4 sH[R] = {};
#pragma unroll
        for (int ch = 0; ch < 8; ++ch) {
            int k0 = (wv << 5) + ch * 4;
            float4 wn[4], wh[4];
#pragma unroll
            for (int p = 0; p < 4; ++p)
                wn[p] = *(const float4*)(Wn + (k0 + p) * Td + 4 * c);
#pragma unroll
            for (int p = 0; p < 4; ++p)
                wh[p] = *(const float4*)(Wh + (k0 + p) * Td + 4 * c);
#pragma unroll
            for (int p = 0; p < 4; ++p) {
                float4 nv = nrow_t[k0 + p];
                FMA4(sN[0], nv.x, wn[p]);  FMA4(sH[0], nv.x, wh[p]);
                FMA4(sN[1], nv.y, wn[p]);  FMA4(sH[1], nv.y, wh[p]);
                FMA4(sN[2], nv.z, wn[p]);  FMA4(sH[2], nv.z, wh[p]);
                FMA4(sN[3], nv.w, wn[p]);  FMA4(sH[3], nv.w, wh[p]);
            }
        }
#pragma unroll
        for (int r = 0; r < R; ++r) { partN[wv][r][c] = sN[r]; partH[wv][r][c] = sH[r]; }
    }
    __syncthreads();

    // Reduce over 8 waves (pre-relu), bias, relu, sum rows, one atomic per col.
    if (t < Td) {
        int c2 = t >> 2, j = t & 3;
        float bnt = bn[t], bht = bh[t];
        float rs1 = 0.f, rs2 = 0.f;
#pragma unroll
        for (int r = 0; r < R; ++r) {
            float v1 = bnt, v2 = bht;
#pragma unroll
            for (int w2 = 0; w2 < 8; ++w2) {
                v1 += ((const float*)&partN[w2][r][c2])[j];
                v2 += ((const float*)&partH[w2][r][c2])[j];
            }
            rs1 += fmaxf(v1, 0.f);
            rs2 += fmaxf(v2, 0.f);
        }
        atomicAdd(&snh[b * Td + t], rs1);
        atomicAdd(&shid[b * Td + t], rs2);
    }
}

// K3: per-batch target row -> ah -> softmax over DIM per head -> mean -> Wa
__global__ __launch_bounds__(256, 1) void k_final(
                        const float* __restrict__ x, const float* __restrict__ emb,
                        const float* __restrict__ Wl, const float* __restrict__ bl,
                        const float* __restrict__ snh, const float* __restrict__ shid,
                        const float* __restrict__ Wa, const float* __restrict__ ba,
                        float* __restrict__ out) {
    int b = blockIdx.x;
    int t = threadIdx.x;
    int tgt = (int)x[(b * (Nn + 1) + Nn) * OBSD + 0];
    tgt = tgt < 0 ? 0 : (tgt > Nn - 1 ? Nn - 1 : tgt);
    __shared__ float erow[Td], lg[Td], pr[Td], od[DIMD];
    __shared__ float4 partL[4][64];
    erow[t] = emb[(b * Nn + tgt) * Td + t];
    __syncthreads();

    int wv = t >> 6, c = t & 63;
    {
        float4 aL = {};
#pragma unroll
        for (int ch = 0; ch < 8; ++ch) {
            int k0 = (wv << 6) + ch * 8;
            float4 w[8];
#pragma unroll
            for (int p = 0; p < 8; ++p)
                w[p] = *(const float4*)(Wl + (k0 + p) * Td + 4 * c);
#pragma unroll
            for (int p = 0; p < 8; ++p) {
                FMA4(aL, erow[k0 + p], w[p]);
            }
        }
        partL[wv][c] = aL;
    }
    __syncthreads();

    int c2 = t >> 2, j = t & 3;
    float acc = bl[t];
#pragma unroll
    for (int w2 = 0; w2 < 4; ++w2) acc += ((const float*)&partL[w2][c2])[j];
    float ah = fmaxf(acc, 0.f);
    lg[t] = ah * snh[b * Td + t];
    __syncthreads();
    int h = t & 7;
    float mx = -1e30f;
#pragma unroll
    for (int d = 0; d < DIMD; ++d) mx = fmaxf(mx, lg[d * HEADS + h]);
    float se = 0.f;
#pragma unroll
    for (int d = 0; d < DIMD; ++d) se += __expf(lg[d * HEADS + h] - mx);
    float attn = __expf(lg[t] - mx) / se;
    pr[t] = attn * shid[b * Td + t];
    __syncthreads();
    if (t < DIMD) {
        float s = 0.f;
#pragma unroll
        for (int hh = 0; hh < HEADS; ++hh) s += pr[t * HEADS + hh];
        od[t] = s * (1.f / HEADS);
    }
    __syncthreads();
    if (t < ACTD) {
        float s = ba[t];
#pragma unroll
        for (int d = 0; d < DIMD; ++d) s = fmaf(od[d], Wa[d * ACTD + t], s);
        out[b * ACTD + t] = s;
    }
}

extern "C" void kernel_launch(void* const* d_in, const int* in_sizes, int n_in,
                              void* d_out, int out_size, void* d_ws, size_t ws_size,
                              hipStream_t stream) {
    const float* x   = (const float*)d_in[0];
    const float* adj = (const float*)d_in[1];
    const float* We1 = (const float*)d_in[2];
    const float* be1 = (const float*)d_in[3];
    const float* We2 = (const float*)d_in[4];
    const float* be2 = (const float*)d_in[5];
    const float* Wl  = (const float*)d_in[6];
    const float* bl  = (const float*)d_in[7];
    const float* Wn  = (const float*)d_in[8];
    const float* bn  = (const float*)d_in[9];
    const float* Wh  = (const float*)d_in[10];
    const float* bh  = (const float*)d_in[11];
    const float* Wa  = (const float*)d_in[12];
    const float* ba  = (const float*)d_in[13];
    float* out = (float*)d_out;

    // ws layout: emb f32[B*N*T] (1 MB) | snh f32[B*T] | shid f32[B*T]
    float* emb  = (float*)d_ws;
    float* snh  = emb + Bsz * Nn * Td;
    float* shid = snh + Bsz * Td;

    k_emb<<<dim3(Bsz * Nn / R), dim3(512), 0, stream>>>(x, We1, be1, We2, be2,
                                                        emb, snh, shid);
    k_fused<<<dim3(Nn / R, Bsz), dim3(512), 0, stream>>>(adj, emb, Wn, bn, Wh, bh,
                                                         snh, shid);
    k_final<<<dim3(Bsz), dim3(256), 0, stream>>>(x, emb, Wl, bl, snh, shid, Wa, ba, out);
}